// Round 6
// baseline (2088.808 us; speedup 1.0000x reference)
//
#include <hip/hip_runtime.h>

// TruncatedHistoryAttn, round 12.
// Phase 1 (unchanged): fp32 tiled GEMM  A = H@W1 (-> ws), B2 = H@W2 (-> d_out).
// Phase 2 = round-11 + LEG HIDING WITHOUT GRID LOSS:
//  - 16 col-slices x 16 batch-pairs = 256 WGs (full grid, unlike round 10's
//    128). Each WG owns 32 cols of batches (pr, pr+16); per-step-pair work =
//    2 x half-size = one round-11 step (work conserved).
//  - Between my b0-publish and my b0-poll sits b1's whole phase -> the LLC
//    publish->detect leg (round 11's dominant exposed term) is mostly hidden:
//    exposed spin = max(0, leg - phase_other).
//  - Wave-local matvec property preserved: thread (kseg=tid>>5, col=tid&31)
//    reads tlds[kseg*32..+32) which lies in its own wave's 64-dim segment.
//  - Exchange per batch: 80 tagged words (64 early j=0..3, 16 late j=4).
//    Poll: sample early words, spin on the 16 late words (lanes 0..15, own
//    slice substituted from register), then re-check early (a step old ->
//    no spin in steady state).
//  - k-reduce: 16 segments = 8 LDS reads/lane-half + 1 shfl_xor(32) (2-way
//    bank aliasing = free). Score sums use width-32 shuffles (halves dup).
// Slot safety: unchanged argument — my poll(t) passing proves every sibling
// passed poll(t-1) (their late j=4 tag-t+1 words are published after their
// poll), so overwriting tag-t words (slot (t+1)&1) at step-t start is safe.
// XCD: bid%8 = pr%8 for all 16 slices -> all siblings of both batches co-XCD.

#define BB 32
#define SS 512
#define DD 512
#define NS 5

#define A_ELEMS    ((size_t)BB * SS * DD)            // 32 MB
#define EXCH_U64_PER_B 256                           // 2 slots x 128 (80 used)
#define EXCH_OFF   (A_ELEMS * 4)
#define EXCH_BYTES ((size_t)BB * EXCH_U64_PER_B * 8) // 64 KB
#define WS_NEED    (EXCH_OFF + EXCH_BYTES)

typedef __attribute__((ext_vector_type(4))) float f32x4;

// ---------------- Phase 1: A = H@W1, B2 = H@W2 (fp32) ----------------
__global__ void __launch_bounds__(256) th_phase1(
    const float* __restrict__ H, const float* __restrict__ W1,
    const float* __restrict__ W2, float* __restrict__ A, float* __restrict__ B2) {
  const int tid = threadIdx.x;
  const int mt = blockIdx.x >> 3;
  const int nt = blockIdx.x & 7;
  const int m0 = mt << 6, n0 = nt << 6;
  __shared__ float Ht[64][20];
  __shared__ float Wt1[16][64];
  __shared__ float Wt2[16][64];
  const int tx = tid & 15, ty = tid >> 4;
  const int sr = tid >> 2, sk = (tid & 3) << 2;
  const int wr = tid >> 4, wn = (tid & 15) << 2;
  float a1[4][4] = {{0.f}}, a2[4][4] = {{0.f}};

  for (int k0 = 0; k0 < DD; k0 += 16) {
    float4 hv  = *(const float4*)&H[(size_t)(m0 + sr) * DD + k0 + sk];
    float4 w1v = *(const float4*)&W1[(size_t)(k0 + wr) * DD + n0 + wn];
    float4 w2v = *(const float4*)&W2[(size_t)(k0 + wr) * DD + n0 + wn];
    *(float4*)&Ht[sr][sk]  = hv;
    *(float4*)&Wt1[wr][wn] = w1v;
    *(float4*)&Wt2[wr][wn] = w2v;
    __syncthreads();
#pragma unroll
    for (int kq = 0; kq < 16; kq += 4) {
      float hs[4][4];
#pragma unroll
      for (int i = 0; i < 4; ++i) {
        float4 h4 = *(const float4*)&Ht[ty * 4 + i][kq];
        hs[i][0] = h4.x; hs[i][1] = h4.y; hs[i][2] = h4.z; hs[i][3] = h4.w;
      }
#pragma unroll
      for (int kk = 0; kk < 4; ++kk) {
        float4 w1f = *(const float4*)&Wt1[kq + kk][tx * 4];
        float4 w2f = *(const float4*)&Wt2[kq + kk][tx * 4];
#pragma unroll
        for (int i = 0; i < 4; ++i) {
          float h = hs[i][kk];
          a1[i][0] = fmaf(h, w1f.x, a1[i][0]);
          a1[i][1] = fmaf(h, w1f.y, a1[i][1]);
          a1[i][2] = fmaf(h, w1f.z, a1[i][2]);
          a1[i][3] = fmaf(h, w1f.w, a1[i][3]);
          a2[i][0] = fmaf(h, w2f.x, a2[i][0]);
          a2[i][1] = fmaf(h, w2f.y, a2[i][1]);
          a2[i][2] = fmaf(h, w2f.z, a2[i][2]);
          a2[i][3] = fmaf(h, w2f.w, a2[i][3]);
        }
      }
    }
    __syncthreads();
  }
#pragma unroll
  for (int i = 0; i < 4; ++i) {
    float4 o1 = make_float4(a1[i][0], a1[i][1], a1[i][2], a1[i][3]);
    float4 o2 = make_float4(a2[i][0], a2[i][1], a2[i][2], a2[i][3]);
    size_t off = (size_t)(m0 + ty * 4 + i) * DD + n0 + tx * 4;
    *(float4*)&A[off]  = o1;
    *(float4*)&B2[off] = o2;
  }
}

// ---------------- Phase 2: one step of one batch ----------------
__device__ __forceinline__ void step_phase(
    const int P, const int t, const int tid, const int q, const int ln,
    const int s, const int col,
    const float* __restrict__ Hb, const float* __restrict__ Ab,
    float* __restrict__ Op, unsigned long long* __restrict__ eb,
    const float (&wa)[32], const float v_col,
    float (&aA)[NS], float (&cC)[NS], float (&tl)[NS],
    float& h_cur, float& btB, float& s4_prev,
    float* tlds_b, float* pm_b, float* wl_b) {
  const bool pub = (t + 1 < SS);

  // ---- prefetches
  float aN_v = 0.f, bt2 = 0.f;
  if (q < NS) {
    aN_v = Ab[(size_t)t * DD + col];                       // A row t
    if (t + 2 < SS) bt2 = Op[(size_t)(t + 2) * DD + col];  // B2 row t+2
  }
  float h_nxt = 0.f;
  if (pub) h_nxt = Hb[(size_t)(t + 1) * DD + tid];

  // ---- waves 1..4: EARLY publish score j=q-1 for step t+1 (rows t-4..t-1)
  if (q >= 1 && q < NS && pub) {
    float aa = aA[(P + 1) % NS];
    aa = (q == 2) ? aA[(P + 2) % NS] : aa;
    aa = (q == 3) ? aA[(P + 3) % NS] : aa;
    aa = (q == 4) ? aA[(P + 4) % NS] : aa;
    float cc = cC[(P + 1) % NS];
    cc = (q == 2) ? cC[(P + 2) % NS] : cc;
    cc = (q == 3) ? cC[(P + 3) % NS] : cc;
    cc = (q == 4) ? cC[(P + 4) % NS] : cc;
    float x = aa + btB + cc;
    float e = __expf(2.0f * x);
    float sc = (1.0f - 2.0f / (e + 1.0f)) * v_col;
    sc += __shfl_xor(sc, 1, 32);
    sc += __shfl_xor(sc, 2, 32);
    sc += __shfl_xor(sc, 4, 32);
    sc += __shfl_xor(sc, 8, 32);
    sc += __shfl_xor(sc, 16, 32);   // width 32: true sum over the 32 cols
    if (ln == 0)
      __hip_atomic_store(&eb[(size_t)((t + 1) & 1) * 128 + (q - 1) * 16 + s],
          (unsigned long long)__float_as_uint(sc) |
              ((unsigned long long)(t + 2) << 32),
          __ATOMIC_RELAXED, __HIP_MEMORY_SCOPE_AGENT);
  }

  // ---- wave 0: poll (early sample -> late spin -> early re-check), softmax
  if (q == 0 && t >= 1) {
    const unsigned long long* wsl = eb + (size_t)(t & 1) * 128;
    // first sample of the 64 early words (j=0..3, all 16 slices)
    unsigned long long we = __hip_atomic_load(&wsl[ln], __ATOMIC_RELAXED,
                                              __HIP_MEMORY_SCOPE_AGENT);
    // spin on the 16 fresh j=4 words (lanes 0..15; own slice from register)
    float pv4 = 0.f;
    if (ln < 16) {
      if (ln == s) {
        pv4 = s4_prev;
      } else {
        unsigned long long w;
        do {
          w = __hip_atomic_load(&wsl[64 + ln], __ATOMIC_RELAXED,
                                __HIP_MEMORY_SCOPE_AGENT);
        } while ((unsigned)(w >> 32) != (unsigned)(t + 1));
        pv4 = __uint_as_float((unsigned)w);
      }
    }
    // early words are a full step old -> usually ready on the first sample
    while ((unsigned)(we >> 32) != (unsigned)(t + 1)) {
      we = __hip_atomic_load(&wsl[ln], __ATOMIC_RELAXED,
                             __HIP_MEMORY_SCOPE_AGENT);
    }
    float pv = __uint_as_float((unsigned)we);
    // reduce over slices: early in 16-lane groups, late in lanes 0..15
    pv += __shfl_xor(pv, 1, 64);
    pv += __shfl_xor(pv, 2, 64);
    pv += __shfl_xor(pv, 4, 64);
    pv += __shfl_xor(pv, 8, 64);
    pv4 += __shfl_xor(pv4, 1, 64);
    pv4 += __shfl_xor(pv4, 2, 64);
    pv4 += __shfl_xor(pv4, 4, 64);
    pv4 += __shfl_xor(pv4, 8, 64);
    float sc0 = __shfl(pv, 0, 64);
    float sc1 = __shfl(pv, 16, 64);
    float sc2 = __shfl(pv, 32, 64);
    float sc3 = __shfl(pv, 48, 64);
    float sc4 = __shfl(pv4, 0, 64);
    float mx = fmaxf(fmaxf(fmaxf(sc0, sc1), fmaxf(sc2, sc3)), sc4);
    float e0 = __expf(sc0 - mx), e1 = __expf(sc1 - mx);
    float e2 = __expf(sc2 - mx), e3 = __expf(sc3 - mx);
    float e4 = __expf(sc4 - mx);
    float inv = 1.0f / (e0 + e1 + e2 + e3 + e4);
    float wv = e0 * inv;
    wv = (ln == 1) ? e1 * inv : wv;
    wv = (ln == 2) ? e2 * inv : wv;
    wv = (ln == 3) ? e3 * inv : wv;
    wv = (ln == 4) ? e4 * inv : wv;
    if (ln < NS) wl_b[ln] = wv;
  }
  __syncthreads();                               // A: weights ready

  // ---- all threads: tilde row (registers + 5 broadcast LDS reads)
  float w0 = wl_b[0], w1 = wl_b[1], w2 = wl_b[2], w3_ = wl_b[3], w4 = wl_b[4];
  float hh = w0 * tl[P % NS];
  hh = fmaf(w1, tl[(P + 1) % NS], hh);
  hh = fmaf(w2, tl[(P + 2) % NS], hh);
  hh = fmaf(w3_, tl[(P + 3) % NS], hh);
  hh = fmaf(w4, tl[(P + 4) % NS], hh);
  float tld = h_cur + fmaxf(hh, 0.f);
  tl[P % NS] = tld;
  tlds_b[tid] = tld;
  if (s == 0) Op[(size_t)t * DD + tid] = tld;    // row t dead (poll passed)
  // wave-local: matvec reads only this wave's own tlds segment
  asm volatile("s_waitcnt lgkmcnt(0)" ::: "memory");

  // ---- matvec: own col, k in [kseg*32, kseg*32+32), wave-uniform reads
  float a0 = 0.f, a1 = 0.f, a2 = 0.f, a3 = 0.f;
  const f32x4* tv = (const f32x4*)&tlds_b[tid & ~31];  // kseg*32
#pragma unroll
  for (int i = 0; i < 8; ++i) {
    f32x4 t4 = tv[i];
    a0 = fmaf(t4.x, wa[4 * i + 0], a0);
    a1 = fmaf(t4.y, wa[4 * i + 1], a1);
    a2 = fmaf(t4.z, wa[4 * i + 2], a2);
    a3 = fmaf(t4.w, wa[4 * i + 3], a3);
  }
  pm_b[tid] = (a0 + a1) + (a2 + a3);
  __syncthreads();                               // C: pm ready

  // ---- waves 0..4: k-reduce + ring update; wave 0: late score j=4, publish
  if (q < NS) {
    const int base = ((ln >> 5) << 8) + (ln & 31);  // half: ksegs 0..7 / 8..15
    float c = 0.f;
#pragma unroll
    for (int k = 0; k < 8; ++k) c += pm_b[base + k * 32];
    c += __shfl_xor(c, 32, 64);                  // both halves: full c[col]
    aA[P % NS] = aN_v;                           // A row t -> slot t%5
    cC[P % NS] = c;                              // c row t -> slot t%5
    if (q == 0 && pub) {
      float x = aN_v + btB + c;                  // row t, bt = row t+1
      float e = __expf(2.0f * x);
      float s4 = (1.0f - 2.0f / (e + 1.0f)) * v_col;
      s4 += __shfl_xor(s4, 1, 32);
      s4 += __shfl_xor(s4, 2, 32);
      s4 += __shfl_xor(s4, 4, 32);
      s4 += __shfl_xor(s4, 8, 32);
      s4 += __shfl_xor(s4, 16, 32);
      if (ln == 0)
        __hip_atomic_store(&eb[(size_t)((t + 1) & 1) * 128 + 64 + s],
            (unsigned long long)__float_as_uint(s4) |
                ((unsigned long long)(t + 2) << 32),
            __ATOMIC_RELAXED, __HIP_MEMORY_SCOPE_AGENT);
      s4_prev = s4;
    }
    btB = bt2;
  }
  h_cur = h_nxt;
}

// grid 256: bid = s*16 + pr; WG = slice s (cols [s*32,s*32+32)) of batches
// pr and pr+16. bid%8 = pr%8 -> all 16 siblings of both batches co-XCD.
__global__ void __launch_bounds__(512) th_phase2(
    const float* __restrict__ H, const float* __restrict__ v,
    const float* __restrict__ W3, const float* __restrict__ A,
    float* __restrict__ Ob,  // d_out: holds B2, overwritten with tilde rows
    unsigned long long* __restrict__ exch) {
  const int tid = threadIdx.x;
  const int pr = blockIdx.x & 15;
  const int s  = blockIdx.x >> 4;    // slice 0..15
  const int q = tid >> 6;            // wave id
  const int ln = tid & 63;
  const int col = (s << 5) + (ln & 31);
  const int kseg = tid >> 5;         // 0..15, 32 k each

  __shared__ float tlds[2][DD];
  __shared__ float pm[2][DD];
  __shared__ float wl[2][8];

  // W3 slice in plain VGPRs (shared by both batches): wa[i] = W3[kseg*32+i][col]
  float wa[32];
#pragma unroll
  for (int i = 0; i < 32; ++i)
    wa[i] = W3[(size_t)(kseg * 32 + i) * DD + col];

  const int b0 = pr, b1 = pr + 16;
  const float* Hb0 = H + (size_t)b0 * SS * DD;
  const float* Hb1 = H + (size_t)b1 * SS * DD;
  const float* Ab0 = A + (size_t)b0 * SS * DD;
  const float* Ab1 = A + (size_t)b1 * SS * DD;
  float* Op0 = Ob + (size_t)b0 * SS * DD;
  float* Op1 = Ob + (size_t)b1 * SS * DD;
  unsigned long long* eb0 = exch + (size_t)b0 * EXCH_U64_PER_B;
  unsigned long long* eb1 = exch + (size_t)b1 * EXCH_U64_PER_B;

  float v_col = (q < NS) ? v[col] : 0.f;
  float aA0[NS] = {0.f, 0.f, 0.f, 0.f, 0.f}, aA1[NS] = {0.f, 0.f, 0.f, 0.f, 0.f};
  float cC0[NS] = {0.f, 0.f, 0.f, 0.f, 0.f}, cC1[NS] = {0.f, 0.f, 0.f, 0.f, 0.f};
  float tl0[NS] = {0.f, 0.f, 0.f, 0.f, 0.f}, tl1[NS] = {0.f, 0.f, 0.f, 0.f, 0.f};
  float s4p0 = 0.f, s4p1 = 0.f;
  float h0 = Hb0[tid], h1 = Hb1[tid];
  float bt0 = 0.f, bt1 = 0.f;
  if (q < NS) {
    bt0 = Op0[DD + col];             // B2 row 1
    bt1 = Op1[DD + col];
  }
  if (tid < NS) { wl[0][tid] = 0.2f; wl[1][tid] = 0.2f; }  // step-0 weights

#pragma unroll 1
  for (int t5 = 0; t5 < 515; t5 += 5) {
#pragma unroll
    for (int p = 0; p < NS; ++p) {
      const int t = t5 + p;
      if (t < SS) {
        step_phase(p, t, tid, q, ln, s, col, Hb0, Ab0, Op0, eb0, wa, v_col,
                   aA0, cC0, tl0, h0, bt0, s4p0, tlds[0], pm[0], wl[0]);
        step_phase(p, t, tid, q, ln, s, col, Hb1, Ab1, Op1, eb1, wa, v_col,
                   aA1, cC1, tl1, h1, bt1, s4p1, tlds[1], pm[1], wl[1]);
      }
    }
  }
}

extern "C" void kernel_launch(void* const* d_in, const int* in_sizes, int n_in,
                              void* d_out, int out_size, void* d_ws, size_t ws_size,
                              hipStream_t stream) {
  const float* H  = (const float*)d_in[0];
  const float* v  = (const float*)d_in[1];
  const float* W1 = (const float*)d_in[2];
  const float* W2 = (const float*)d_in[3];
  const float* W3 = (const float*)d_in[4];
  float* out = (float*)d_out;

  if (ws_size < WS_NEED) return;

  float* A = (float*)d_ws;
  unsigned long long* exch = (unsigned long long*)((char*)d_ws + EXCH_OFF);

  (void)hipMemsetAsync(exch, 0, EXCH_BYTES, stream);
  hipLaunchKernelGGL(th_phase1, dim3(256 * 8), dim3(256), 0, stream,
                     H, W1, W2, A, out);
  hipLaunchKernelGGL(th_phase2, dim3(256), dim3(512), 0, stream,
                     H, v, W3, A, out, exch);
}

// Round 7
// 1717.100 us; speedup vs baseline: 1.2165x; 1.2165x over previous
//
#include <hip/hip_runtime.h>

// TruncatedHistoryAttn, round 13.
// Phase 1 (unchanged): fp32 tiled GEMM  A = H@W1 (-> ws), B2 = H@W2 (-> d_out).
// Phase 2 = round-11 (best: 1010us) + SAME-XCD L2 EXCHANGE:
//  - Round-12 post-mortem: two-batch interleave couples through shared
//    barriers (poll spin holds all waves) -> reverted to round-11 skeleton.
//  - Round-11's remaining cost is the agent-scope exchange: publish and spin
//    both traverse the fabric to the LLC (~2x 700-1000cy). All 8 siblings of
//    a batch are co-XCD (bid%8 = b%8, mod-8 rr dispatch), so the exchange can
//    ride the XCD-local L2: sc0 stores (write-through to L2) + sc0 loads
//    (bypass L1, hit shared L2) ~200-300cy RTT. No HIP scope maps to this ->
//    inline asm global_load/store_dwordx2 with sc0.
//  - SAFETY: the XCD mapping is a heuristic, not guaranteed. Every publish is
//    dual-written: fast sc0 word (L2) + agent word (LLC, disjoint offset).
//    Poll spins on fast; after 16 tries alternates checking the agent word.
//    If the mapping ever changes we degrade to round-11 speed, never hang.
//    Tags make either copy independently sufficient; inter-kernel flushes +
//    memset kill cross-iteration stale tags.
// Kept from round 11: early distributed publish (waves 1..4 publish j=0..3 at
// step start; wave 0 publishes j=4 at tail), wave-0-only poll with self-j4
// register substitute, wave-local ds_read_b128 matvec, 2 barriers/step.

#define BB 32
#define SS 512
#define DD 512
#define NS 5

#define A_ELEMS    ((size_t)BB * SS * DD)            // 32 MB
// per batch: fast 2 slots x 64 at [0,128) + slow 2 slots x 64 at [128,256)
#define EXCH_U64_PER_B 256
#define EXCH_OFF   (A_ELEMS * 4)
#define EXCH_BYTES ((size_t)BB * EXCH_U64_PER_B * 8) // 64 KB
#define WS_NEED    (EXCH_OFF + EXCH_BYTES)

typedef __attribute__((ext_vector_type(4))) float f32x4;

// ---- XCD-L2 exchange primitives (sc0: L1-bypass, L2 coherence point) ----
__device__ __forceinline__ unsigned long long l2_load_u64(
    const unsigned long long* p) {
  unsigned long long r;
  asm volatile("global_load_dwordx2 %0, %1, off sc0\n\ts_waitcnt vmcnt(0)"
               : "=v"(r) : "v"(p) : "memory");
  return r;
}
__device__ __forceinline__ void l2_store_u64(unsigned long long* p,
                                             unsigned long long x) {
  asm volatile("global_store_dwordx2 %0, %1, off sc0"
               :: "v"(p), "v"(x) : "memory");
}

// ---------------- Phase 1: A = H@W1, B2 = H@W2 (fp32) ----------------
__global__ void __launch_bounds__(256) th_phase1(
    const float* __restrict__ H, const float* __restrict__ W1,
    const float* __restrict__ W2, float* __restrict__ A, float* __restrict__ B2) {
  const int tid = threadIdx.x;
  const int mt = blockIdx.x >> 3;
  const int nt = blockIdx.x & 7;
  const int m0 = mt << 6, n0 = nt << 6;
  __shared__ float Ht[64][20];
  __shared__ float Wt1[16][64];
  __shared__ float Wt2[16][64];
  const int tx = tid & 15, ty = tid >> 4;
  const int sr = tid >> 2, sk = (tid & 3) << 2;
  const int wr = tid >> 4, wn = (tid & 15) << 2;
  float a1[4][4] = {{0.f}}, a2[4][4] = {{0.f}};

  for (int k0 = 0; k0 < DD; k0 += 16) {
    float4 hv  = *(const float4*)&H[(size_t)(m0 + sr) * DD + k0 + sk];
    float4 w1v = *(const float4*)&W1[(size_t)(k0 + wr) * DD + n0 + wn];
    float4 w2v = *(const float4*)&W2[(size_t)(k0 + wr) * DD + n0 + wn];
    *(float4*)&Ht[sr][sk]  = hv;
    *(float4*)&Wt1[wr][wn] = w1v;
    *(float4*)&Wt2[wr][wn] = w2v;
    __syncthreads();
#pragma unroll
    for (int kq = 0; kq < 16; kq += 4) {
      float hs[4][4];
#pragma unroll
      for (int i = 0; i < 4; ++i) {
        float4 h4 = *(const float4*)&Ht[ty * 4 + i][kq];
        hs[i][0] = h4.x; hs[i][1] = h4.y; hs[i][2] = h4.z; hs[i][3] = h4.w;
      }
#pragma unroll
      for (int kk = 0; kk < 4; ++kk) {
        float4 w1f = *(const float4*)&Wt1[kq + kk][tx * 4];
        float4 w2f = *(const float4*)&Wt2[kq + kk][tx * 4];
#pragma unroll
        for (int i = 0; i < 4; ++i) {
          float h = hs[i][kk];
          a1[i][0] = fmaf(h, w1f.x, a1[i][0]);
          a1[i][1] = fmaf(h, w1f.y, a1[i][1]);
          a1[i][2] = fmaf(h, w1f.z, a1[i][2]);
          a1[i][3] = fmaf(h, w1f.w, a1[i][3]);
          a2[i][0] = fmaf(h, w2f.x, a2[i][0]);
          a2[i][1] = fmaf(h, w2f.y, a2[i][1]);
          a2[i][2] = fmaf(h, w2f.z, a2[i][2]);
          a2[i][3] = fmaf(h, w2f.w, a2[i][3]);
        }
      }
    }
    __syncthreads();
  }
#pragma unroll
  for (int i = 0; i < 4; ++i) {
    float4 o1 = make_float4(a1[i][0], a1[i][1], a1[i][2], a1[i][3]);
    float4 o2 = make_float4(a2[i][0], a2[i][1], a2[i][2], a2[i][3]);
    size_t off = (size_t)(m0 + ty * 4 + i) * DD + n0 + tx * 4;
    *(float4*)&A[off]  = o1;
    *(float4*)&B2[off] = o2;
  }
}

// ---------------- Phase 2: the recurrence ----------------
// grid 256 = 8 WGs/batch; bid = g*32+b -> bid%8 = b%8 -> all siblings co-XCD.
__global__ void __launch_bounds__(512) th_phase2(
    const float* __restrict__ H, const float* __restrict__ v,
    const float* __restrict__ W3, const float* __restrict__ A,
    float* __restrict__ Ob,  // d_out: holds B2, overwritten with tilde rows
    unsigned long long* __restrict__ exch) {
  const int tid = threadIdx.x;
  const int b = blockIdx.x & 31;
  const int g = blockIdx.x >> 5;     // 0..7: cols [g*64, g*64+64)
  const int q = tid >> 6;            // wave id == k-segment 0..7
  const int ln = tid & 63;
  const int col = (g << 6) + ln;

  __shared__ float tlds[DD];         // tilde_t row
  __shared__ float pm[DD];           // matvec k-segment partials
  __shared__ float wl[8];            // softmax weights broadcast

  // W3 slice in plain VGPRs: wa[i] = W3[q*64+i][col]
  float wa[64];
#pragma unroll
  for (int i = 0; i < 64; ++i)
    wa[i] = W3[(size_t)(q * 64 + i) * DD + col];

  const float* Hb = H + (size_t)b * SS * DD;
  const float* Ab = A + (size_t)b * SS * DD;
  float* Op = Ob + (size_t)b * SS * DD;
  unsigned long long* ebF = exch + (size_t)b * EXCH_U64_PER_B;        // fast/L2
  unsigned long long* ebS = ebF + 128;                                 // slow/LLC

  // waves 0..4: replica rings over this WG's 64 cols (row s in slot s%5)
  float v_col = (q < NS) ? v[col] : 0.f;
  float aA[NS] = {0.f, 0.f, 0.f, 0.f, 0.f};
  float cC[NS] = {0.f, 0.f, 0.f, 0.f, 0.f};
  float tl[NS] = {0.f, 0.f, 0.f, 0.f, 0.f};
  float s4_prev = 0.f;               // wave 0: own j=4 score (self-substitute)
  float h_cur = Hb[tid];
  float btB = (q < NS) ? Op[DD + col] : 0.f;  // B2 row t+1 (init: row 1)

  if (tid < NS) wl[tid] = 0.2f;      // step-0 weights: exactly uniform

#pragma unroll 1
  for (int t5 = 0; t5 < 515; t5 += 5) {
#pragma unroll
    for (int p = 0; p < NS; ++p) {
      const int t = t5 + p;
      if (t < SS) {
        const bool pub = (t + 1 < SS);

        // ---- prefetches
        float aN_v = 0.f, bt2 = 0.f;
        if (q < NS) {
          aN_v = Ab[(size_t)t * DD + col];                  // A row t
          if (t + 2 < SS) bt2 = Op[(size_t)(t + 2) * DD + col];  // B2 row t+2
        }
        float h_nxt = 0.f;
        if (pub) h_nxt = Hb[(size_t)(t + 1) * DD + tid];

        // ---- waves 1..4: EARLY publish of score j=q-1 for step t+1
        if (q >= 1 && q < NS && pub) {
          float aa = aA[(p + 1) % NS];
          aa = (q == 2) ? aA[(p + 2) % NS] : aa;
          aa = (q == 3) ? aA[(p + 3) % NS] : aa;
          aa = (q == 4) ? aA[(p + 4) % NS] : aa;
          float cc = cC[(p + 1) % NS];
          cc = (q == 2) ? cC[(p + 2) % NS] : cc;
          cc = (q == 3) ? cC[(p + 3) % NS] : cc;
          cc = (q == 4) ? cC[(p + 4) % NS] : cc;
          float x = aa + btB + cc;
          float e = __expf(2.0f * x);
          float s = (1.0f - 2.0f / (e + 1.0f)) * v_col;
#pragma unroll
          for (int off = 32; off >= 1; off >>= 1) s += __shfl_xor(s, off, 64);
          if (ln == 0) {
            const size_t idx = (size_t)((t + 1) & 1) * 64 + (q - 1) * 8 + g;
            unsigned long long w = (unsigned long long)__float_as_uint(s) |
                                   ((unsigned long long)(t + 2) << 32);
            l2_store_u64(&ebF[idx], w);
            __hip_atomic_store(&ebS[idx], w, __ATOMIC_RELAXED,
                               __HIP_MEMORY_SCOPE_AGENT);
          }
        }

        // ---- wave 0: hybrid poll (slot t&1, tag t+1) -> softmax -> wl
        if (q == 0 && t >= 1) {
          const size_t sb = (size_t)(t & 1) * 64;
          float pv = 0.f;
          if (ln < 40) {
            if (!((ln >> 3) == 4 && (ln & 7) == g)) {
              const unsigned want = (unsigned)(t + 1);
              unsigned long long w = l2_load_u64(&ebF[sb + ln]);
              int tries = 0;
              while ((unsigned)(w >> 32) != want) {
                ++tries;
                if (tries >= 16 && (tries & 1))
                  w = __hip_atomic_load(&ebS[sb + ln], __ATOMIC_RELAXED,
                                        __HIP_MEMORY_SCOPE_AGENT);
                else
                  w = l2_load_u64(&ebF[sb + ln]);
              }
              pv = __uint_as_float((unsigned)w);
            } else {
              pv = s4_prev;
            }
          }
          pv += __shfl_xor(pv, 1, 64);
          pv += __shfl_xor(pv, 2, 64);
          pv += __shfl_xor(pv, 4, 64);   // each 8-group holds its j-total
          float sc0 = __shfl(pv, 0, 64);
          float sc1 = __shfl(pv, 8, 64);
          float sc2 = __shfl(pv, 16, 64);
          float sc3 = __shfl(pv, 24, 64);
          float sc4 = __shfl(pv, 32, 64);
          float mx = fmaxf(fmaxf(fmaxf(sc0, sc1), fmaxf(sc2, sc3)), sc4);
          float e0 = __expf(sc0 - mx), e1 = __expf(sc1 - mx);
          float e2 = __expf(sc2 - mx), e3 = __expf(sc3 - mx);
          float e4 = __expf(sc4 - mx);
          float inv = 1.0f / (e0 + e1 + e2 + e3 + e4);
          float wv = e0 * inv;
          wv = (ln == 1) ? e1 * inv : wv;
          wv = (ln == 2) ? e2 * inv : wv;
          wv = (ln == 3) ? e3 * inv : wv;
          wv = (ln == 4) ? e4 * inv : wv;
          if (ln < NS) wl[ln] = wv;
        }
        __syncthreads();                           // A: weights ready

        // ---- all threads: tilde row (registers + 5 broadcast LDS reads)
        float w0 = wl[0], w1 = wl[1], w2 = wl[2], w3_ = wl[3], w4 = wl[4];
        float hh = w0 * tl[p];
        hh = fmaf(w1, tl[(p + 1) % NS], hh);
        hh = fmaf(w2, tl[(p + 2) % NS], hh);
        hh = fmaf(w3_, tl[(p + 3) % NS], hh);
        hh = fmaf(w4, tl[(p + 4) % NS], hh);
        float tld = h_cur + fmaxf(hh, 0.f);
        tl[p] = tld;
        tlds[tid] = tld;
        if (g == 0) Op[(size_t)t * DD + tid] = tld;  // row t dead (poll passed)
        // wave-local: matvec reads ONLY this wave's own tlds segment
        asm volatile("s_waitcnt lgkmcnt(0)" ::: "memory");

        // ---- matvec: own 64 cols, k in [q*64, q*64+64), wave-uniform reads
        float a0 = 0.f, a1 = 0.f, a2 = 0.f, a3 = 0.f;
        const f32x4* tv = (const f32x4*)&tlds[q << 6];
#pragma unroll
        for (int i = 0; i < 16; ++i) {
          f32x4 t4 = tv[i];
          a0 = fmaf(t4.x, wa[4 * i + 0], a0);
          a1 = fmaf(t4.y, wa[4 * i + 1], a1);
          a2 = fmaf(t4.z, wa[4 * i + 2], a2);
          a3 = fmaf(t4.w, wa[4 * i + 3], a3);
        }
        pm[tid] = (a0 + a1) + (a2 + a3);
        __syncthreads();                           // C: pm ready

        // ---- waves 0..4: k-reduce + ring update; wave 0: score j=4, publish
        if (q < NS) {
          float c = 0.f;
#pragma unroll
          for (int s = 0; s < 8; ++s) c += pm[s * 64 + ln];
          aA[p] = aN_v;                            // A row t -> slot t%5
          cC[p] = c;                               // c row t -> slot t%5
          if (q == 0 && pub) {
            float x = aN_v + btB + c;              // row t, bt = row t+1
            float e = __expf(2.0f * x);
            float s4 = (1.0f - 2.0f / (e + 1.0f)) * v_col;
#pragma unroll
            for (int off = 32; off >= 1; off >>= 1) s4 += __shfl_xor(s4, off, 64);
            if (ln == 0) {
              const size_t idx = (size_t)((t + 1) & 1) * 64 + 32 + g;
              unsigned long long w = (unsigned long long)__float_as_uint(s4) |
                                     ((unsigned long long)(t + 2) << 32);
              l2_store_u64(&ebF[idx], w);
              __hip_atomic_store(&ebS[idx], w, __ATOMIC_RELAXED,
                                 __HIP_MEMORY_SCOPE_AGENT);
            }
            s4_prev = s4;
          }
          btB = bt2;
        }
        h_cur = h_nxt;
      }
    }
  }
}

extern "C" void kernel_launch(void* const* d_in, const int* in_sizes, int n_in,
                              void* d_out, int out_size, void* d_ws, size_t ws_size,
                              hipStream_t stream) {
  const float* H  = (const float*)d_in[0];
  const float* v  = (const float*)d_in[1];
  const float* W1 = (const float*)d_in[2];
  const float* W2 = (const float*)d_in[3];
  const float* W3 = (const float*)d_in[4];
  float* out = (float*)d_out;

  if (ws_size < WS_NEED) return;

  float* A = (float*)d_ws;
  unsigned long long* exch = (unsigned long long*)((char*)d_ws + EXCH_OFF);

  (void)hipMemsetAsync(exch, 0, EXCH_BYTES, stream);
  hipLaunchKernelGGL(th_phase1, dim3(256 * 8), dim3(256), 0, stream,
                     H, W1, W2, A, out);
  hipLaunchKernelGGL(th_phase2, dim3(BB * 8), dim3(512), 0, stream,
                     H, v, W3, A, out, exch);
}

// Round 9
// 1131.538 us; speedup vs baseline: 1.8460x; 1.5175x over previous
//
#include <hip/hip_runtime.h>

// TruncatedHistoryAttn, round 15 (= round 14 with the DPP builtin fixed:
// __builtin_amdgcn_update_dpp needs CONSTANT args -> template parameters).
// Phase 1 (unchanged): fp32 tiled GEMM  A = H@W1 (-> ws), B2 = H@W2 (-> d_out).
// Phase 2 = round-11 (best: 1010us) with DPP cross-lane sums:
//  - Round-13 post-mortem: sc0 stores stay dirty in the writer's L2 (no LLC
//    write-through) -> fast word never visible; reverted to agent words only.
//  - Round-11's local critical path: three DEPENDENT 6-op __shfl_xor chains
//    (ds_bpermute ~50-120cy each): s4 tail sum (~650cy, delays the only fresh
//    publish), early-score sums (~600cy, delay barrier A), poll combine
//    (~350cy post-detect). All replaced with DPP v_add_f32 reductions
//    (rocPRIM sequence, ~10cy/hop): full 64-lane sum lands in lane 63.
//  - Publishes issue from lane 63; wave-0's own j=4 (s4_prev) re-broadcast
//    with one shfl AFTER the publish (off-critical).
//  - Poll combine: xor1/2/4 via 3 DPP ops (8-lane groups), then 5 independent
//    broadcast shfls.
// Kept from round 11: tagged 8B agent words (store IS the publication), early
// distributed publish (waves 1..4 at step start, j=4 at tail), wave-0-only
// poll with self-j4 register substitute, wave-local ds_read_b128 matvec,
// 2 barriers/step, grid 256.

#define BB 32
#define SS 512
#define DD 512
#define NS 5

#define A_ELEMS    ((size_t)BB * SS * DD)            // 32 MB
#define EXCH_U64_PER_B 128                           // 2 slots x 64 (40 used)
#define EXCH_OFF   (A_ELEMS * 4)
#define EXCH_BYTES ((size_t)BB * EXCH_U64_PER_B * 8) // 32 KB
#define WS_NEED    (EXCH_OFF + EXCH_BYTES)

typedef __attribute__((ext_vector_type(4))) float f32x4;

// ---- DPP cross-lane sum (rocPRIM sequence); ctrl words are template consts.
template <int CTRL, int RMASK, int BMASK, bool BC>
__device__ __forceinline__ float dpp_term(float x) {
  return __uint_as_float((unsigned)__builtin_amdgcn_update_dpp(
      0, (int)__float_as_uint(x), CTRL, RMASK, BMASK, BC));
}
__device__ __forceinline__ float wave_sum64(float x) {
  x += dpp_term<0xB1, 0xF, 0xF, true>(x);   // quad_perm [1,0,3,2] (xor 1)
  x += dpp_term<0x4E, 0xF, 0xF, true>(x);   // quad_perm [2,3,0,1] (xor 2)
  x += dpp_term<0x141, 0xF, 0xF, true>(x);  // row_half_mirror     (xor 4)
  x += dpp_term<0x140, 0xF, 0xF, true>(x);  // row_mirror          (xor 8)
  x += dpp_term<0x142, 0xA, 0xF, false>(x); // row_bcast15 -> rows 1,3
  x += dpp_term<0x143, 0xC, 0xF, false>(x); // row_bcast31 -> rows 2,3
  return x;                                 // lane 63: sum of all 64
}
// sum within each 8-lane group (every lane ends with its group's sum)
__device__ __forceinline__ float group8_sum(float x) {
  x += dpp_term<0xB1, 0xF, 0xF, true>(x);
  x += dpp_term<0x4E, 0xF, 0xF, true>(x);
  x += dpp_term<0x141, 0xF, 0xF, true>(x);
  return x;
}

// ---------------- Phase 1: A = H@W1, B2 = H@W2 (fp32) ----------------
__global__ void __launch_bounds__(256) th_phase1(
    const float* __restrict__ H, const float* __restrict__ W1,
    const float* __restrict__ W2, float* __restrict__ A, float* __restrict__ B2) {
  const int tid = threadIdx.x;
  const int mt = blockIdx.x >> 3;
  const int nt = blockIdx.x & 7;
  const int m0 = mt << 6, n0 = nt << 6;
  __shared__ float Ht[64][20];
  __shared__ float Wt1[16][64];
  __shared__ float Wt2[16][64];
  const int tx = tid & 15, ty = tid >> 4;
  const int sr = tid >> 2, sk = (tid & 3) << 2;
  const int wr = tid >> 4, wn = (tid & 15) << 2;
  float a1[4][4] = {{0.f}}, a2[4][4] = {{0.f}};

  for (int k0 = 0; k0 < DD; k0 += 16) {
    float4 hv  = *(const float4*)&H[(size_t)(m0 + sr) * DD + k0 + sk];
    float4 w1v = *(const float4*)&W1[(size_t)(k0 + wr) * DD + n0 + wn];
    float4 w2v = *(const float4*)&W2[(size_t)(k0 + wr) * DD + n0 + wn];
    *(float4*)&Ht[sr][sk]  = hv;
    *(float4*)&Wt1[wr][wn] = w1v;
    *(float4*)&Wt2[wr][wn] = w2v;
    __syncthreads();
#pragma unroll
    for (int kq = 0; kq < 16; kq += 4) {
      float hs[4][4];
#pragma unroll
      for (int i = 0; i < 4; ++i) {
        float4 h4 = *(const float4*)&Ht[ty * 4 + i][kq];
        hs[i][0] = h4.x; hs[i][1] = h4.y; hs[i][2] = h4.z; hs[i][3] = h4.w;
      }
#pragma unroll
      for (int kk = 0; kk < 4; ++kk) {
        float4 w1f = *(const float4*)&Wt1[kq + kk][tx * 4];
        float4 w2f = *(const float4*)&Wt2[kq + kk][tx * 4];
#pragma unroll
        for (int i = 0; i < 4; ++i) {
          float h = hs[i][kk];
          a1[i][0] = fmaf(h, w1f.x, a1[i][0]);
          a1[i][1] = fmaf(h, w1f.y, a1[i][1]);
          a1[i][2] = fmaf(h, w1f.z, a1[i][2]);
          a1[i][3] = fmaf(h, w1f.w, a1[i][3]);
          a2[i][0] = fmaf(h, w2f.x, a2[i][0]);
          a2[i][1] = fmaf(h, w2f.y, a2[i][1]);
          a2[i][2] = fmaf(h, w2f.z, a2[i][2]);
          a2[i][3] = fmaf(h, w2f.w, a2[i][3]);
        }
      }
    }
    __syncthreads();
  }
#pragma unroll
  for (int i = 0; i < 4; ++i) {
    float4 o1 = make_float4(a1[i][0], a1[i][1], a1[i][2], a1[i][3]);
    float4 o2 = make_float4(a2[i][0], a2[i][1], a2[i][2], a2[i][3]);
    size_t off = (size_t)(m0 + ty * 4 + i) * DD + n0 + tx * 4;
    *(float4*)&A[off]  = o1;
    *(float4*)&B2[off] = o2;
  }
}

// ---------------- Phase 2: the recurrence ----------------
// grid 256 = 8 WGs/batch.
__global__ void __launch_bounds__(512) th_phase2(
    const float* __restrict__ H, const float* __restrict__ v,
    const float* __restrict__ W3, const float* __restrict__ A,
    float* __restrict__ Ob,  // d_out: holds B2, overwritten with tilde rows
    unsigned long long* __restrict__ exch) {
  const int tid = threadIdx.x;
  const int b = blockIdx.x & 31;
  const int g = blockIdx.x >> 5;     // 0..7: cols [g*64, g*64+64)
  const int q = tid >> 6;            // wave id == k-segment 0..7
  const int ln = tid & 63;
  const int col = (g << 6) + ln;

  __shared__ float tlds[DD];         // tilde_t row
  __shared__ float pm[DD];           // matvec k-segment partials
  __shared__ float wl[8];            // softmax weights broadcast

  // W3 slice in plain VGPRs: wa[i] = W3[q*64+i][col]
  float wa[64];
#pragma unroll
  for (int i = 0; i < 64; ++i)
    wa[i] = W3[(size_t)(q * 64 + i) * DD + col];

  const float* Hb = H + (size_t)b * SS * DD;
  const float* Ab = A + (size_t)b * SS * DD;
  float* Op = Ob + (size_t)b * SS * DD;
  unsigned long long* eb = exch + (size_t)b * EXCH_U64_PER_B;

  // waves 0..4: replica rings over this WG's 64 cols (row s in slot s%5)
  float v_col = (q < NS) ? v[col] : 0.f;
  float aA[NS] = {0.f, 0.f, 0.f, 0.f, 0.f};
  float cC[NS] = {0.f, 0.f, 0.f, 0.f, 0.f};
  float tl[NS] = {0.f, 0.f, 0.f, 0.f, 0.f};
  float s4_prev = 0.f;               // wave 0: own j=4 score (all lanes)
  float h_cur = Hb[tid];
  float btB = (q < NS) ? Op[DD + col] : 0.f;  // B2 row t+1 (init: row 1)

  if (tid < NS) wl[tid] = 0.2f;      // step-0 weights: exactly uniform

#pragma unroll 1
  for (int t5 = 0; t5 < 515; t5 += 5) {
#pragma unroll
    for (int p = 0; p < NS; ++p) {
      const int t = t5 + p;
      if (t < SS) {
        const bool pub = (t + 1 < SS);

        // ---- prefetches
        float aN_v = 0.f, bt2 = 0.f;
        if (q < NS) {
          aN_v = Ab[(size_t)t * DD + col];                  // A row t
          if (t + 2 < SS) bt2 = Op[(size_t)(t + 2) * DD + col];  // B2 row t+2
        }
        float h_nxt = 0.f;
        if (pub) h_nxt = Hb[(size_t)(t + 1) * DD + tid];

        // ---- waves 1..4: EARLY publish of score j=q-1 for step t+1
        if (q >= 1 && q < NS && pub) {
          float aa = aA[(p + 1) % NS];
          aa = (q == 2) ? aA[(p + 2) % NS] : aa;
          aa = (q == 3) ? aA[(p + 3) % NS] : aa;
          aa = (q == 4) ? aA[(p + 4) % NS] : aa;
          float cc = cC[(p + 1) % NS];
          cc = (q == 2) ? cC[(p + 2) % NS] : cc;
          cc = (q == 3) ? cC[(p + 3) % NS] : cc;
          cc = (q == 4) ? cC[(p + 4) % NS] : cc;
          float x = aa + btB + cc;
          float e = __expf(2.0f * x);
          float s = (1.0f - 2.0f / (e + 1.0f)) * v_col;
          s = wave_sum64(s);                       // lane 63 = total
          if (ln == 63)
            __hip_atomic_store(&eb[(size_t)((t + 1) & 1) * 64 + (q - 1) * 8 + g],
                (unsigned long long)__float_as_uint(s) |
                    ((unsigned long long)(t + 2) << 32),
                __ATOMIC_RELAXED, __HIP_MEMORY_SCOPE_AGENT);
        }

        // ---- wave 0: poll tagged words (slot t&1, tag t+1) -> softmax -> wl
        if (q == 0 && t >= 1) {
          const unsigned long long* wsl = eb + (size_t)(t & 1) * 64;
          float pv = 0.f;
          if (ln < 40) {
            if (!((ln >> 3) == 4 && (ln & 7) == g)) {
              unsigned long long w;
              do {
                w = __hip_atomic_load(&wsl[ln], __ATOMIC_RELAXED,
                                      __HIP_MEMORY_SCOPE_AGENT);
              } while ((unsigned)(w >> 32) != (unsigned)(t + 1));
              pv = __uint_as_float((unsigned)w);
            } else {
              pv = s4_prev;
            }
          }
          pv = group8_sum(pv);             // each 8-group holds its j-total
          float sc0 = __shfl(pv, 0, 64);
          float sc1 = __shfl(pv, 8, 64);
          float sc2 = __shfl(pv, 16, 64);
          float sc3 = __shfl(pv, 24, 64);
          float sc4 = __shfl(pv, 32, 64);
          float mx = fmaxf(fmaxf(fmaxf(sc0, sc1), fmaxf(sc2, sc3)), sc4);
          float e0 = __expf(sc0 - mx), e1 = __expf(sc1 - mx);
          float e2 = __expf(sc2 - mx), e3 = __expf(sc3 - mx);
          float e4 = __expf(sc4 - mx);
          float inv = 1.0f / (e0 + e1 + e2 + e3 + e4);
          float wv = e0 * inv;
          wv = (ln == 1) ? e1 * inv : wv;
          wv = (ln == 2) ? e2 * inv : wv;
          wv = (ln == 3) ? e3 * inv : wv;
          wv = (ln == 4) ? e4 * inv : wv;
          if (ln < NS) wl[ln] = wv;
        }
        __syncthreads();                           // A: weights ready

        // ---- all threads: tilde row (registers + 5 broadcast LDS reads)
        float w0 = wl[0], w1 = wl[1], w2 = wl[2], w3_ = wl[3], w4 = wl[4];
        float hh = w0 * tl[p];
        hh = fmaf(w1, tl[(p + 1) % NS], hh);
        hh = fmaf(w2, tl[(p + 2) % NS], hh);
        hh = fmaf(w3_, tl[(p + 3) % NS], hh);
        hh = fmaf(w4, tl[(p + 4) % NS], hh);
        float tld = h_cur + fmaxf(hh, 0.f);
        tl[p] = tld;
        tlds[tid] = tld;
        if (g == 0) Op[(size_t)t * DD + tid] = tld;  // row t dead (poll passed)
        // wave-local: matvec reads ONLY this wave's own tlds segment
        asm volatile("s_waitcnt lgkmcnt(0)" ::: "memory");

        // ---- matvec: own 64 cols, k in [q*64, q*64+64), wave-uniform reads
        float a0 = 0.f, a1 = 0.f, a2 = 0.f, a3 = 0.f;
        const f32x4* tv = (const f32x4*)&tlds[q << 6];
#pragma unroll
        for (int i = 0; i < 16; ++i) {
          f32x4 t4 = tv[i];
          a0 = fmaf(t4.x, wa[4 * i + 0], a0);
          a1 = fmaf(t4.y, wa[4 * i + 1], a1);
          a2 = fmaf(t4.z, wa[4 * i + 2], a2);
          a3 = fmaf(t4.w, wa[4 * i + 3], a3);
        }
        pm[tid] = (a0 + a1) + (a2 + a3);
        __syncthreads();                           // C: pm ready

        // ---- waves 0..4: k-reduce + ring update; wave 0: score j=4, publish
        if (q < NS) {
          float c = 0.f;
#pragma unroll
          for (int s = 0; s < 8; ++s) c += pm[s * 64 + ln];
          aA[p] = aN_v;                            // A row t -> slot t%5
          cC[p] = c;                               // c row t -> slot t%5
          if (q == 0 && pub) {
            float x = aN_v + btB + c;              // row t, bt = row t+1
            float e = __expf(2.0f * x);
            float s4 = (1.0f - 2.0f / (e + 1.0f)) * v_col;
            s4 = wave_sum64(s4);                   // lane 63 = total
            if (ln == 63)
              __hip_atomic_store(&eb[(size_t)((t + 1) & 1) * 64 + 32 + g],
                  (unsigned long long)__float_as_uint(s4) |
                      ((unsigned long long)(t + 2) << 32),
                  __ATOMIC_RELAXED, __HIP_MEMORY_SCOPE_AGENT);
            s4_prev = __shfl(s4, 63, 64);          // off-critical broadcast
          }
          btB = bt2;
        }
        h_cur = h_nxt;
      }
    }
  }
}

extern "C" void kernel_launch(void* const* d_in, const int* in_sizes, int n_in,
                              void* d_out, int out_size, void* d_ws, size_t ws_size,
                              hipStream_t stream) {
  const float* H  = (const float*)d_in[0];
  const float* v  = (const float*)d_in[1];
  const float* W1 = (const float*)d_in[2];
  const float* W2 = (const float*)d_in[3];
  const float* W3 = (const float*)d_in[4];
  float* out = (float*)d_out;

  if (ws_size < WS_NEED) return;

  float* A = (float*)d_ws;
  unsigned long long* exch = (unsigned long long*)((char*)d_ws + EXCH_OFF);

  (void)hipMemsetAsync(exch, 0, EXCH_BYTES, stream);
  hipLaunchKernelGGL(th_phase1, dim3(256 * 8), dim3(256), 0, stream,
                     H, W1, W2, A, out);
  hipLaunchKernelGGL(th_phase2, dim3(BB * 8), dim3(512), 0, stream,
                     H, v, W3, A, out, exch);
}